// Round 18
// baseline (194.653 us; speedup 1.0000x reference)
//
#include <hip/hip_runtime.h>
#include <hip/hip_bf16.h>
#include <math.h>

#define BATCH  64
#define SEQ    2048
#define DMODEL 512
#define ATT    256
#define M_TOTAL (BATCH * SEQ)

#define MT     64                       // rows per block
#define KC     32                       // k per chunk
#define NCHUNK 16
#define PSZ    8192                     // ushorts per 16 KB plane (ATT*KC)
#define WA_LO_OFF (NCHUNK * PSZ)        // ushort offset of lo images

#define NBLK   (M_TOTAL / MT)           // 2048 fused blocks
#define BPB    (SEQ / MT)               // 32 blocks per batch row

// d_ws layout
#define PF_OFF  (1u << 20)                              // 4 MB: [2048][512] f32
#define ML_OFF  (PF_OFF + (size_t)NBLK * DMODEL * 4)    // 16 KB: [2048] float2
#define BS_OFF  (ML_OFF + (size_t)NBLK * 8)             // 512 B: [64] float2

typedef __attribute__((ext_vector_type(8))) short short8v;
typedef __attribute__((ext_vector_type(4))) float floatx4;

__device__ __forceinline__ ushort f2bf_rne(float f) {
    unsigned u = __float_as_uint(f);
    u += 0x7FFFu + ((u >> 16) & 1u);
    return (ushort)(u >> 16);
}
__device__ __forceinline__ float bf2f(ushort h) {
    return __uint_as_float(((unsigned)h) << 16);
}
__device__ __forceinline__ void gll16(const void* g, void* l) {
    __builtin_amdgcn_global_load_lds(
        (const __attribute__((address_space(1))) unsigned*)g,
        (__attribute__((address_space(3))) unsigned*)l, 16, 0, 0);
}
// sign-free fast tanh: 1 - 2/(e^{2x}+1); exact at +-inf, 0
__device__ __forceinline__ float fast_tanh(float x) {
    return 1.0f - 2.0f * __builtin_amdgcn_rcpf(__expf(x + x) + 1.0f);
}
// float4 -> packed bf16 hi (truncation) + lo (RNE of remainder)
__device__ __forceinline__ void cvt4(float4 v, uint2& hi, uint2& lo) {
    unsigned u0 = __float_as_uint(v.x), u1 = __float_as_uint(v.y);
    unsigned u2 = __float_as_uint(v.z), u3 = __float_as_uint(v.w);
    hi.x = __builtin_amdgcn_perm(u1, u0, 0x07060302u);   // [bf(y):bf(x)]
    hi.y = __builtin_amdgcn_perm(u3, u2, 0x07060302u);
    float r0 = v.x - __uint_as_float(u0 & 0xFFFF0000u);
    float r1 = v.y - __uint_as_float(u1 & 0xFFFF0000u);
    float r2 = v.z - __uint_as_float(u2 & 0xFFFF0000u);
    float r3 = v.w - __uint_as_float(u3 & 0xFFFF0000u);
    asm("v_cvt_pk_bf16_f32 %0, %1, %2" : "=v"(lo.x) : "v"(r0), "v"(r1));
    asm("v_cvt_pk_bf16_f32 %0, %1, %2" : "=v"(lo.y) : "v"(r2), "v"(r3));
}
__device__ __forceinline__ void cvt8(float4 a, float4 b, uint4& hi, uint4& lo) {
    uint2 h0, l0, h1, l1;
    cvt4(a, h0, l0);
    cvt4(b, h1, l1);
    hi = make_uint4(h0.x, h0.y, h1.x, h1.y);
    lo = make_uint4(l0.x, l0.y, l1.x, l1.y);
}

// K0: Wa fp32 [256][512] -> bf16 hi/lo per-chunk quad-major images:
// elem (a, k): chunk kc=k>>5, quad q=(k&31)>>3 -> kc*8192 + (q*256+a)*8 + (k&7)
__global__ __launch_bounds__(256)
void wa_convert_kernel(const float* __restrict__ Wa, ushort* __restrict__ out) {
    int idx = blockIdx.x * 256 + threadIdx.x;   // 131072
    float x = Wa[idx];
    ushort hi = f2bf_rne(x);
    ushort lo = f2bf_rne(x - bf2f(hi));
    int a = idx >> 9, k = idx & 511;
    int kc = k >> 5, kk = k & 31, q = kk >> 3;
    size_t o = (size_t)kc * PSZ + (size_t)(q * 256 + a) * 8 + (kk & 7);
    out[o] = hi;
    out[WA_LO_OFF + o] = lo;
}

// KF: fused scores GEMM + tanh-reduce + block softmax + partial GEVM,
// PRODUCER/CONSUMER wave specialization.
// 384 thr / 6 waves: waves 0-3 = consumers (tile 32x128: wm=wid>>1, wn=wid&1;
// acc=64 regs; A per-lane regs, 1-chunk prefetch); waves 4-5 = producers
// (B gll only: wave4 hi plane, wave5 lo; vmcnt(0) BEFORE the shared barrier
// so L2 latency overlaps consumer MFMAs). Double-buffered B (2x32 KB).
// One s_barrier per chunk. 66 KB LDS, 170-reg budget -> 2 blocks/CU.
__global__ __launch_bounds__(384, 3)
void fused_kernel(const float* __restrict__ X,
                  const ushort* __restrict__ wa_cvt,
                  const float* __restrict__ ba,
                  const float* __restrict__ ae,
                  float* __restrict__ zg,
                  float* __restrict__ pfeat,
                  float2* __restrict__ pml) {
    __shared__ __align__(16) ushort bbuf[2][2 * PSZ];  // 64 KB: 2 x (hi|lo)
    __shared__ float zb[2][MT];
    __shared__ float pbuf[MT];

    const int tid = threadIdx.x;
    const int l   = tid & 63;
    const int wid = tid >> 6;
    const int m0  = blockIdx.x * MT;

    floatx4 acc[2][8];
    #pragma unroll
    for (int i = 0; i < 2; ++i)
        #pragma unroll
        for (int j = 0; j < 8; ++j)
            acc[i][j] = (floatx4){0.f, 0.f, 0.f, 0.f};

    const int wm = (wid >> 1) & 1, wn = wid & 1;       // consumer coords
    const int n  = l & 15, g = l >> 4;

    if (wid >= 4) {
        // ================= PRODUCER (waves 4,5) =================
        const int plane = wid - 4;                     // 0: hi, 1: lo
        const char* src = (const char*)wa_cvt
                          + (size_t)plane * (WA_LO_OFF * 2) + l * 16;
        // stage chunk 0 -> buf0
        {
            char* dst = (char*)&bbuf[0][0] + plane * 16384;
            #pragma unroll
            for (int i = 0; i < 16; ++i)
                gll16(src + i * 1024, dst + i * 1024);
        }
        asm volatile("s_waitcnt vmcnt(0)" ::: "memory");
        __builtin_amdgcn_s_barrier();
        #pragma unroll 1
        for (int t = 0; t < NCHUNK; ++t) {
            if (t + 1 < NCHUNK) {
                const char* s2 = src + (size_t)(t + 1) * 16384;
                char* dst = (char*)&bbuf[(t + 1) & 1][0] + plane * 16384;
                #pragma unroll
                for (int i = 0; i < 16; ++i)
                    gll16(s2 + i * 1024, dst + i * 1024);
                asm volatile("s_waitcnt vmcnt(0)" ::: "memory");
            }
            __builtin_amdgcn_s_barrier();   // handoff: buf[(t+1)&1] ready
        }
    } else {
        // ================= CONSUMER (waves 0-3) =================
        // A: lane rows = m0 + wm*32 + {0,16} + n, k-window g*8; bumped ptrs.
        const float* ap0 = X + (size_t)(m0 + wm * 32 + n) * DMODEL + g * 8;
        const float* ap1 = ap0 + 16 * DMODEL;
        // B frag base (quad-major): (g*256 + col)*8, col = wn*128 + nj*16 + n
        const int bb = (g * 256 + wn * 128 + n) * 8;

        // issue A(0)
        float4 xr0[2], xr1[2];
        xr0[0] = *(const float4*)(ap0);
        xr1[0] = *(const float4*)(ap0 + 4);
        xr0[1] = *(const float4*)(ap1);
        xr1[1] = *(const float4*)(ap1 + 4);
        ap0 += KC; ap1 += KC;
        __builtin_amdgcn_s_barrier();      // buf0 ready (producer drained)

        #pragma unroll 1
        for (int t = 0; t < NCHUNK; ++t) {
            const ushort* bh_t = &bbuf[t & 1][0];
            const ushort* bl_t = bh_t + PSZ;

            // convert this chunk's A (loads arrived during previous chunk)
            short8v ah[2], av[2];
            cvt8(xr0[0], xr1[0], *(uint4*)&ah[0], *(uint4*)&av[0]);
            cvt8(xr0[1], xr1[1], *(uint4*)&ah[1], *(uint4*)&av[1]);

            // issue next-chunk A (in flight across this chunk's MFMAs)
            if (t + 1 < NCHUNK) {
                xr0[0] = *(const float4*)(ap0);
                xr1[0] = *(const float4*)(ap0 + 4);
                xr0[1] = *(const float4*)(ap1);
                xr1[1] = *(const float4*)(ap1 + 4);
                ap0 += KC; ap1 += KC;
            }

            // compute: 16 b128 B-frag reads + 48 MFMAs
            __builtin_amdgcn_s_setprio(1);
            #pragma unroll
            for (int nj = 0; nj < 8; ++nj) {
                short8v bh = *(const short8v*)&bh_t[bb + nj * 128];
                short8v bv = *(const short8v*)&bl_t[bb + nj * 128];
                #pragma unroll
                for (int mi = 0; mi < 2; ++mi) {
                    acc[mi][nj] = __builtin_amdgcn_mfma_f32_16x16x32_bf16(av[mi], bh, acc[mi][nj], 0, 0, 0);
                    acc[mi][nj] = __builtin_amdgcn_mfma_f32_16x16x32_bf16(ah[mi], bv, acc[mi][nj], 0, 0, 0);
                    acc[mi][nj] = __builtin_amdgcn_mfma_f32_16x16x32_bf16(ah[mi], bh, acc[mi][nj], 0, 0, 0);
                }
            }
            __builtin_amdgcn_s_setprio(0);
            __builtin_amdgcn_s_barrier();  // join producer handoff
        }
    }

    // ================= common epilogue (all 6 waves) =================
    if (wid < 4) {
        // z: row = wm*32 + mi*16 + g*4 + e, col = wn*128 + nj*16 + n
        float bav[8], aev[8];
        #pragma unroll
        for (int nj = 0; nj < 8; ++nj) {
            int c = wn * 128 + nj * 16 + n;
            bav[nj] = ba[c];
            aev[nj] = ae[c];
        }
        #pragma unroll
        for (int mi = 0; mi < 2; ++mi) {
            float zp[4] = {0.f, 0.f, 0.f, 0.f};
            #pragma unroll
            for (int nj = 0; nj < 8; ++nj)
                #pragma unroll
                for (int e = 0; e < 4; ++e)
                    zp[e] += fast_tanh(acc[mi][nj][e] + bav[nj]) * aev[nj];
            #pragma unroll
            for (int off = 8; off >= 1; off >>= 1)
                #pragma unroll
                for (int e = 0; e < 4; ++e)
                    zp[e] += __shfl_xor(zp[e], off, 64);
            if (n == 0)
                *(float4*)&zb[wn][wm * 32 + mi * 16 + g * 4] =
                    make_float4(zp[0], zp[1], zp[2], zp[3]);
        }
    }
    __syncthreads();

    // block softmax partials over 64 rows (single wave)
    if (tid < MT) {
        float zsum = zb[0][tid] + zb[1][tid];
        zg[m0 + tid] = zsum;
        float m = zsum;
        #pragma unroll
        for (int off = 32; off >= 1; off >>= 1)
            m = fmaxf(m, __shfl_xor(m, off, 64));
        float p = __expf(zsum - m);
        pbuf[tid] = p;
        float s = p;
        #pragma unroll
        for (int off = 32; off >= 1; off >>= 1)
            s += __shfl_xor(s, off, 64);
        if (tid == 0) pml[blockIdx.x] = make_float2(m, s);
    }
    __syncthreads();

    // partial feature GEVM: pfeat[blk][f] = sum_s p[s]*X[m0+s][f] (L2-hot)
    if (tid < 256) {
        float a0 = 0.f, a1 = 0.f;
        const float* xc = X + (size_t)m0 * DMODEL + tid;
        #pragma unroll 4
        for (int s = 0; s < MT; ++s) {
            float ps = pbuf[s];
            a0 = fmaf(xc[(size_t)s * DMODEL], ps, a0);
            a1 = fmaf(xc[(size_t)s * DMODEL + 256], ps, a1);
        }
        pfeat[(size_t)blockIdx.x * DMODEL + tid]       = a0;
        pfeat[(size_t)blockIdx.x * DMODEL + tid + 256] = a1;
    }
}

// K-combine: per batch, merge 32 block partials with online-softmax rescale.
__global__ __launch_bounds__(512)
void combine_kernel(const float* __restrict__ pfeat, const float2* __restrict__ pml,
                    float* __restrict__ feat, float2* __restrict__ bstat) {
    const int b = blockIdx.x, tid = threadIdx.x;
    float M = -3.0e38f;
    #pragma unroll
    for (int c = 0; c < BPB; ++c)
        M = fmaxf(M, pml[b * BPB + c].x);
    float L = 0.f, s = 0.f;
    #pragma unroll 4
    for (int c = 0; c < BPB; ++c) {
        float2 ml = pml[b * BPB + c];
        float sc = __expf(ml.x - M);
        L += sc * ml.y;
        s = fmaf(sc, pfeat[(size_t)(b * BPB + c) * DMODEL + tid], s);
    }
    feat[(size_t)b * DMODEL + tid] = s / L;
    if (tid == 0) bstat[b] = make_float2(M, L);
}

// K-weights: w[b,s] = exp(z - M_b) / L_b, in place over zg.
__global__ __launch_bounds__(256)
void weights_kernel(float* __restrict__ zw, const float2* __restrict__ bstat) {
    int i = blockIdx.x * 256 + threadIdx.x;   // 131072
    float2 ml = bstat[i >> 11];               // SEQ = 2048
    zw[i] = __expf(zw[i] - ml.x) / ml.y;
}

extern "C" void kernel_launch(void* const* d_in, const int* in_sizes, int n_in,
                              void* d_out, int out_size, void* d_ws, size_t ws_size,
                              hipStream_t stream) {
    const float* X  = (const float*)d_in[0];
    const float* Wa = (const float*)d_in[1];
    const float* ba = (const float*)d_in[2];
    const float* ae = (const float*)d_in[3];
    float* out  = (float*)d_out;
    float* feat = out;                       // [64][512]
    float* wgt  = out + BATCH * DMODEL;      // [64][2048]; holds z then weights

    ushort* wa_cvt  = (ushort*)d_ws;                          // 512 KB
    float*  pfeat   = (float*)((char*)d_ws + PF_OFF);         // 4 MB
    float2* pml     = (float2*)((char*)d_ws + ML_OFF);        // 16 KB
    float2* bstat   = (float2*)((char*)d_ws + BS_OFF);        // 512 B

    wa_convert_kernel<<<ATT * DMODEL / 256, 256, 0, stream>>>(Wa, wa_cvt);
    fused_kernel<<<NBLK, 384, 0, stream>>>(X, wa_cvt, ba, ae, wgt, pfeat, pml);
    combine_kernel<<<BATCH, 512, 0, stream>>>(pfeat, pml, feat, bstat);
    weights_kernel<<<M_TOTAL / 256, 256, 0, stream>>>(wgt, bstat);
}

// Round 19
// 135.694 us; speedup vs baseline: 1.4345x; 1.4345x over previous
//
#include <hip/hip_runtime.h>
#include <hip/hip_bf16.h>
#include <math.h>

#define BATCH  64
#define SEQ    2048
#define DMODEL 512
#define ATT    256
#define M_TOTAL (BATCH * SEQ)

#define MT     128                      // rows per block
#define KC     32                       // k per chunk
#define NCHUNK 16
#define PSZ    8192                     // ushorts per 16 KB B plane (ATT*KC)
#define WA_LO_OFF (NCHUNK * PSZ)        // ushort offset of lo images

#define NBLK   (M_TOTAL / MT)           // 1024 fused blocks
#define BPB    (SEQ / MT)               // 16 blocks per batch row

// d_ws layout
#define PF_OFF  (1u << 20)                              // 2 MB: [1024][512] f32
#define ML_OFF  (PF_OFF + (size_t)NBLK * DMODEL * 4)    // 8 KB: [1024] float2
#define BS_OFF  (ML_OFF + (size_t)NBLK * 8)             // 512 B: [64] float2

typedef __attribute__((ext_vector_type(8))) short short8v;
typedef __attribute__((ext_vector_type(4))) float floatx4;

__device__ __forceinline__ ushort f2bf_rne(float f) {
    unsigned u = __float_as_uint(f);
    u += 0x7FFFu + ((u >> 16) & 1u);
    return (ushort)(u >> 16);
}
__device__ __forceinline__ float bf2f(ushort h) {
    return __uint_as_float(((unsigned)h) << 16);
}
__device__ __forceinline__ void gll16(const void* g, void* l) {
    __builtin_amdgcn_global_load_lds(
        (const __attribute__((address_space(1))) unsigned*)g,
        (__attribute__((address_space(3))) unsigned*)l, 16, 0, 0);
}
// sign-free fast tanh: 1 - 2/(e^{2x}+1); exact at +-inf, 0
__device__ __forceinline__ float fast_tanh(float x) {
    return 1.0f - 2.0f * __builtin_amdgcn_rcpf(__expf(x + x) + 1.0f);
}
// float4 -> packed bf16 hi (truncation) + lo (RNE of remainder)
__device__ __forceinline__ void cvt4(float4 v, uint2& hi, uint2& lo) {
    unsigned u0 = __float_as_uint(v.x), u1 = __float_as_uint(v.y);
    unsigned u2 = __float_as_uint(v.z), u3 = __float_as_uint(v.w);
    hi.x = __builtin_amdgcn_perm(u1, u0, 0x07060302u);   // [bf(y):bf(x)]
    hi.y = __builtin_amdgcn_perm(u3, u2, 0x07060302u);
    float r0 = v.x - __uint_as_float(u0 & 0xFFFF0000u);
    float r1 = v.y - __uint_as_float(u1 & 0xFFFF0000u);
    float r2 = v.z - __uint_as_float(u2 & 0xFFFF0000u);
    float r3 = v.w - __uint_as_float(u3 & 0xFFFF0000u);
    asm("v_cvt_pk_bf16_f32 %0, %1, %2" : "=v"(lo.x) : "v"(r0), "v"(r1));
    asm("v_cvt_pk_bf16_f32 %0, %1, %2" : "=v"(lo.y) : "v"(r2), "v"(r3));
}
__device__ __forceinline__ void cvt8(float4 a, float4 b, uint4& hi, uint4& lo) {
    uint2 h0, l0, h1, l1;
    cvt4(a, h0, l0);
    cvt4(b, h1, l1);
    hi = make_uint4(h0.x, h0.y, h1.x, h1.y);
    lo = make_uint4(l0.x, l0.y, l1.x, l1.y);
}

// K0: Wa fp32 [256][512] -> bf16 hi/lo per-chunk quad-major images:
// elem (a, k): chunk kc=k>>5, quad q=(k&31)>>3 -> kc*8192 + (q*256+a)*8 + (k&7)
__global__ __launch_bounds__(256)
void wa_convert_kernel(const float* __restrict__ Wa, ushort* __restrict__ out) {
    int idx = blockIdx.x * 256 + threadIdx.x;   // 131072
    float x = Wa[idx];
    ushort hi = f2bf_rne(x);
    ushort lo = f2bf_rne(x - bf2f(hi));
    int a = idx >> 9, k = idx & 511;
    int kc = k >> 5, kk = k & 31, q = kk >> 3;
    size_t o = (size_t)kc * PSZ + (size_t)(q * 256 + a) * 8 + (kk & 7);
    out[o] = hi;
    out[WA_LO_OFF + o] = lo;
}

// KF: fused scores GEMM + tanh-reduce + block softmax + partial GEVM.
// R11 structure + A DOUBLE-BUFFER: 512 thr / 8 waves; tile 128x256; wave
// (wm=wid>>1, wn=wid&1) owns rows [wm*32,+32) x cols [wn*128,+128).
// A staged fp32 via gll (quad-XOR pre-swizzled source) into 2x16KB dbuf —
// A(t+1) issues at TOP of chunk t so HBM latency hides under the MFMAs;
// B single-buffered 32 KB (refill after read-done barrier costs ~L2 only).
// 67 KB LDS, <=128 unified regs -> 2 blocks/CU.
__global__ __launch_bounds__(512, 4)
void fused_kernel(const float* __restrict__ X,
                  const ushort* __restrict__ wa_cvt,
                  const float* __restrict__ ba,
                  const float* __restrict__ ae,
                  float* __restrict__ zg,
                  float* __restrict__ pfeat,
                  float2* __restrict__ pml) {
    __shared__ __align__(16) float  abuf[2][MT * KC];  // 2 x 16 KB fp32 A
    __shared__ __align__(16) ushort bbuf[2 * PSZ];     // 32 KB: hi 16K | lo 16K
    __shared__ float zb[2][MT];
    __shared__ float pbuf[MT];
    __shared__ float redm[2], redl[2];

    const int tid = threadIdx.x;
    const int l   = tid & 63;
    const int wid = tid >> 6;
    const int wm  = wid >> 1, wn = wid & 1;
    const int n   = l & 15, g = l >> 4;
    const int m0  = blockIdx.x * MT;

    // A gll sources (R11-verified): slot s=(wid*2+j)*64+l; row=s>>3,
    // qp=(s>>1)&3, half=s&1; logical quad at phys qp is qp^(row&3).
    const float* asrc[2];
    {
        #pragma unroll
        for (int j = 0; j < 2; ++j) {
            int s = (wid * 2 + j) * 64 + l;
            int row = s >> 3, qp = (s >> 1) & 3, half = s & 1;
            asrc[j] = X + (size_t)(m0 + row) * DMODEL
                        + ((qp ^ (row & 3)) << 3) + (half << 2);
        }
    }
    // B gll (R13-verified): waves 0-3 hi plane, 4-7 lo; bumped pointer.
    const char* bsrc = (const char*)(wid < 4 ? wa_cvt : wa_cvt + WA_LO_OFF)
                       + (wid & 3) * 4096 + l * 16;
    char* const bdst = (char*)bbuf + wid * 4096;
    // fragment offsets
    const int bb = (g * 256 + wn * 128 + n) * 8;       // B quad-major ushorts
    int afo[2];                                         // A byte offsets
    #pragma unroll
    for (int mi = 0; mi < 2; ++mi) {
        int ar = wm * 32 + mi * 16 + n;
        afo[mi] = ar * 128 + ((g ^ (ar & 3)) << 5);
    }

    floatx4 acc[2][8];
    #pragma unroll
    for (int i = 0; i < 2; ++i)
        #pragma unroll
        for (int j = 0; j < 8; ++j)
            acc[i][j] = (floatx4){0.f, 0.f, 0.f, 0.f};

    // ---- prologue: stage A(0)->abuf[0], B(0)->bbuf; drain; barrier ----
    #pragma unroll
    for (int j = 0; j < 2; ++j)
        gll16(asrc[j], (char*)&abuf[0][0] + (wid * 2 + j) * 1024);
    #pragma unroll
    for (int i = 0; i < 4; ++i)
        gll16(bsrc + i * 1024, bdst + i * 1024);
    bsrc += 16384;
    asm volatile("s_waitcnt vmcnt(0)" ::: "memory");
    __builtin_amdgcn_s_barrier();

    #pragma unroll 1
    for (int kc = 0; kc < NCHUNK; ++kc) {
        const int cur = kc & 1;
        const bool more = (kc + 1 < NCHUNK);
        const char* ab = (const char*)&abuf[cur][0];

        // A fragments: fp32 from LDS -> hi/lo bf16 in regs
        short8v ah[2], av[2];
        #pragma unroll
        for (int mi = 0; mi < 2; ++mi) {
            float4 f0 = *(const float4*)(ab + afo[mi]);
            float4 f1 = *(const float4*)(ab + afo[mi] + 16);
            cvt8(f0, f1, *(uint4*)&ah[mi], *(uint4*)&av[mi]);
        }

        // issue A(t+1) glls NOW — a full chunk of MFMAs covers HBM latency
        if (more) {
            char* ad = (char*)&abuf[cur ^ 1][0] + wid * 2048;
            gll16(asrc[0] + (kc + 1) * KC, ad);
            gll16(asrc[1] + (kc + 1) * KC, ad + 1024);
        }
        asm volatile("" ::: "memory");

        // compute: 16 b128 B-frag reads + 48 MFMAs, prioritized
        __builtin_amdgcn_s_setprio(1);
        #pragma unroll
        for (int nj = 0; nj < 8; ++nj) {
            short8v bh = *(const short8v*)&bbuf[bb + nj * 128];
            short8v bv = *(const short8v*)&bbuf[PSZ + bb + nj * 128];
            #pragma unroll
            for (int mi = 0; mi < 2; ++mi) {
                acc[mi][nj] = __builtin_amdgcn_mfma_f32_16x16x32_bf16(av[mi], bh, acc[mi][nj], 0, 0, 0);
                acc[mi][nj] = __builtin_amdgcn_mfma_f32_16x16x32_bf16(ah[mi], bv, acc[mi][nj], 0, 0, 0);
                acc[mi][nj] = __builtin_amdgcn_mfma_f32_16x16x32_bf16(ah[mi], bh, acc[mi][nj], 0, 0, 0);
            }
        }
        __builtin_amdgcn_s_setprio(0);

        if (more) {
            __builtin_amdgcn_s_barrier();      // all waves done reading B(t)
            #pragma unroll
            for (int i = 0; i < 4; ++i)
                gll16(bsrc + i * 1024, bdst + i * 1024);
            bsrc += 16384;
            // drains B(t+1) (~L2); A(t+1) has been flying a full chunk
            asm volatile("s_waitcnt vmcnt(0)" ::: "memory");
            __builtin_amdgcn_s_barrier();      // bbuf + abuf[cur^1] ready
        }
    }

    // ---- z epilogue: row = wm*32 + mi*16 + g*4 + e, col = wn*128 + nj*16 + n
    float bav[8], aev[8];
    #pragma unroll
    for (int nj = 0; nj < 8; ++nj) {
        int c = wn * 128 + nj * 16 + n;
        bav[nj] = ba[c];
        aev[nj] = ae[c];
    }
    #pragma unroll
    for (int mi = 0; mi < 2; ++mi) {
        float zp[4] = {0.f, 0.f, 0.f, 0.f};
        #pragma unroll
        for (int nj = 0; nj < 8; ++nj)
            #pragma unroll
            for (int e = 0; e < 4; ++e)
                zp[e] += fast_tanh(acc[mi][nj][e] + bav[nj]) * aev[nj];
        #pragma unroll
        for (int off = 8; off >= 1; off >>= 1)
            #pragma unroll
            for (int e = 0; e < 4; ++e)
                zp[e] += __shfl_xor(zp[e], off, 64);
        if (n == 0)
            *(float4*)&zb[wn][wm * 32 + mi * 16 + g * 4] =
                make_float4(zp[0], zp[1], zp[2], zp[3]);
    }
    __syncthreads();

    // ---- block softmax partials over 128 rows (waves 0-1)
    float zsum = 0.f;
    if (tid < MT) {
        zsum = zb[0][tid] + zb[1][tid];
        zg[m0 + tid] = zsum;
        float mloc = zsum;
        #pragma unroll
        for (int off = 32; off >= 1; off >>= 1)
            mloc = fmaxf(mloc, __shfl_xor(mloc, off, 64));
        if (l == 0) redm[wid] = mloc;
    }
    __syncthreads();
    if (tid < MT) {
        float M = fmaxf(redm[0], redm[1]);
        float p = __expf(zsum - M);
        pbuf[tid] = p;
        float s = p;
        #pragma unroll
        for (int off = 32; off >= 1; off >>= 1)
            s += __shfl_xor(s, off, 64);
        if (l == 0) redl[wid] = s;
    }
    __syncthreads();
    if (tid == 0)
        pml[blockIdx.x] = make_float2(fmaxf(redm[0], redm[1]), redl[0] + redl[1]);

    // ---- partial feature GEVM: pfeat[blk][f] = sum_s p[s]*X[m0+s][f] (L2-hot)
    {
        float a0 = 0.f, a1 = 0.f, a2 = 0.f, a3 = 0.f;
        const float* xc = X + (size_t)m0 * DMODEL + tid;
        #pragma unroll 8
        for (int s = 0; s < MT; s += 4) {
            a0 = fmaf(xc[(size_t)(s + 0) * DMODEL], pbuf[s + 0], a0);
            a1 = fmaf(xc[(size_t)(s + 1) * DMODEL], pbuf[s + 1], a1);
            a2 = fmaf(xc[(size_t)(s + 2) * DMODEL], pbuf[s + 2], a2);
            a3 = fmaf(xc[(size_t)(s + 3) * DMODEL], pbuf[s + 3], a3);
        }
        pfeat[(size_t)blockIdx.x * DMODEL + tid] = (a0 + a1) + (a2 + a3);
    }
}

// K-combine: per batch, merge 16 block partials with online-softmax rescale.
__global__ __launch_bounds__(512)
void combine_kernel(const float* __restrict__ pfeat, const float2* __restrict__ pml,
                    float* __restrict__ feat, float2* __restrict__ bstat) {
    const int b = blockIdx.x, tid = threadIdx.x;
    float M = -3.0e38f;
    #pragma unroll
    for (int c = 0; c < BPB; ++c)
        M = fmaxf(M, pml[b * BPB + c].x);
    float L = 0.f, s = 0.f;
    #pragma unroll 4
    for (int c = 0; c < BPB; ++c) {
        float2 ml = pml[b * BPB + c];
        float sc = __expf(ml.x - M);
        L += sc * ml.y;
        s = fmaf(sc, pfeat[(size_t)(b * BPB + c) * DMODEL + tid], s);
    }
    feat[(size_t)b * DMODEL + tid] = s / L;
    if (tid == 0) bstat[b] = make_float2(M, L);
}

// K-weights: w[b,s] = exp(z - M_b) / L_b, in place over zg.
__global__ __launch_bounds__(256)
void weights_kernel(float* __restrict__ zw, const float2* __restrict__ bstat) {
    int i = blockIdx.x * 256 + threadIdx.x;   // 131072
    float2 ml = bstat[i >> 11];               // SEQ = 2048
    zw[i] = __expf(zw[i] - ml.x) / ml.y;
}

extern "C" void kernel_launch(void* const* d_in, const int* in_sizes, int n_in,
                              void* d_out, int out_size, void* d_ws, size_t ws_size,
                              hipStream_t stream) {
    const float* X  = (const float*)d_in[0];
    const float* Wa = (const float*)d_in[1];
    const float* ba = (const float*)d_in[2];
    const float* ae = (const float*)d_in[3];
    float* out  = (float*)d_out;
    float* feat = out;                       // [64][512]
    float* wgt  = out + BATCH * DMODEL;      // [64][2048]; holds z then weights

    ushort* wa_cvt  = (ushort*)d_ws;                          // 512 KB
    float*  pfeat   = (float*)((char*)d_ws + PF_OFF);         // 2 MB
    float2* pml     = (float2*)((char*)d_ws + ML_OFF);        // 8 KB
    float2* bstat   = (float2*)((char*)d_ws + BS_OFF);        // 512 B

    wa_convert_kernel<<<ATT * DMODEL / 256, 256, 0, stream>>>(Wa, wa_cvt);
    fused_kernel<<<NBLK, 512, 0, stream>>>(X, wa_cvt, ba, ae, wgt, pfeat, pml);
    combine_kernel<<<BATCH, 512, 0, stream>>>(pfeat, pml, feat, bstat);
    weights_kernel<<<M_TOTAL / 256, 256, 0, stream>>>(wgt, bstat);
}